// Round 2
// baseline (358.472 us; speedup 1.0000x reference)
//
#include <hip/hip_runtime.h>
#include <hip/hip_bf16.h>
#include <math.h>

// Sliding-window attention, fp32 baseline (round 1).
// Phase 1: fused QKV projection GEMM (C = A @ W^T), 64x64x64 tiles.
// Phase 2: windowed attention, 1 wave per (t, head); block = 4 consecutive t
//          of the SAME head so K/V windows overlap in L1 (round-1 fix).
// Phase 3: output projection GEMM (same kernel, grid.z = 1).

#define TILE 64
#define BKK  64
#define LDST (TILE + 4)   // LDS row stride 68 floats: keeps float4 alignment

__global__ __launch_bounds__(256) void gemm_nt_f32(
    const float* __restrict__ A,
    const float* __restrict__ W0, const float* __restrict__ W1, const float* __restrict__ W2,
    float* __restrict__ C0, float* __restrict__ C1, float* __restrict__ C2,
    int M, int N, int K)
{
    const float* W; float* C;
    if (blockIdx.z == 0)      { W = W0; C = C0; }
    else if (blockIdx.z == 1) { W = W1; C = C1; }
    else                      { W = W2; C = C2; }

    // K-major LDS tiles: inner loop reads contiguous float4 per thread.
    __shared__ float As[BKK][LDST];
    __shared__ float Ws[BKK][LDST];

    const int tid = threadIdx.x;
    const int tx = tid & 15;        // 16 cols of 4 outputs
    const int ty = tid >> 4;        // 16 rows of 4 outputs
    const int m0 = blockIdx.y * TILE;
    const int n0 = blockIdx.x * TILE;

    const int lr = tid >> 4;        // load row 0..15 (stepped by 16)
    const int lc = (tid & 15) << 2; // load col (k) 0..60

    float acc[4][4] = {};

    for (int k0 = 0; k0 < K; k0 += BKK) {
        #pragma unroll
        for (int r = 0; r < TILE; r += 16) {
            float4 a = *(const float4*)(A + (size_t)(m0 + lr + r) * K + k0 + lc);
            float4 w = *(const float4*)(W + (size_t)(n0 + lr + r) * K + k0 + lc);
            // transpose into K-major LDS
            As[lc + 0][lr + r] = a.x; As[lc + 1][lr + r] = a.y;
            As[lc + 2][lr + r] = a.z; As[lc + 3][lr + r] = a.w;
            Ws[lc + 0][lr + r] = w.x; Ws[lc + 1][lr + r] = w.y;
            Ws[lc + 2][lr + r] = w.z; Ws[lc + 3][lr + r] = w.w;
        }
        __syncthreads();

        #pragma unroll 8
        for (int kk = 0; kk < BKK; ++kk) {
            float4 av = *(const float4*)&As[kk][ty << 2];
            float4 bv = *(const float4*)&Ws[kk][tx << 2];
            const float a4[4] = {av.x, av.y, av.z, av.w};
            const float b4[4] = {bv.x, bv.y, bv.z, bv.w};
            #pragma unroll
            for (int i = 0; i < 4; ++i)
                #pragma unroll
                for (int j = 0; j < 4; ++j)
                    acc[i][j] = fmaf(a4[i], b4[j], acc[i][j]);
        }
        __syncthreads();
    }

    #pragma unroll
    for (int i = 0; i < 4; ++i) {
        float4 o = make_float4(acc[i][0], acc[i][1], acc[i][2], acc[i][3]);
        *(float4*)(C + (size_t)(m0 + (ty << 2) + i) * N + n0 + (tx << 2)) = o;
    }
}

// One wave per (t, h). Block = 4 waves handling t..t+3 of the SAME head so
// the 64-row K/V windows overlap in L1. Lane = window pos for QK^T;
// lane = head dim for PV. T=4096, D=512, H=8, Dh=64, window=64, scale=8.
__global__ __launch_bounds__(256) void swattn_f32(
    const float* __restrict__ Q, const float* __restrict__ K,
    const float* __restrict__ V, float* __restrict__ O, int T)
{
    __shared__ float ps[4][64];
    const int wave = threadIdx.x >> 6;
    const int lane = threadIdx.x & 63;
    // blockIdx.x enumerates (h, t/4): consecutive waves share the head.
    const int h = blockIdx.x / (T / 4);
    const int t = (blockIdx.x % (T / 4)) * 4 + wave;

    const float* qrow = Q + (size_t)t * 512 + h * 64;
    const int kt = t - 63 + lane;

    float s = -INFINITY;
    if (kt >= 0) {
        const float* krow = K + (size_t)kt * 512 + h * 64;
        float acc = 0.f;
        #pragma unroll
        for (int d = 0; d < 64; d += 4) {
            float4 qa = *(const float4*)(qrow + d);
            float4 ka = *(const float4*)(krow + d);
            acc = fmaf(qa.x, ka.x, acc);
            acc = fmaf(qa.y, ka.y, acc);
            acc = fmaf(qa.z, ka.z, acc);
            acc = fmaf(qa.w, ka.w, acc);
        }
        s = acc * 0.125f;   // 1/sqrt(64)
    }

    // wave softmax (64 lanes)
    float m = s;
    #pragma unroll
    for (int off = 32; off > 0; off >>= 1) m = fmaxf(m, __shfl_xor(m, off));
    float p = (kt >= 0) ? __expf(s - m) : 0.f;
    float sum = p;
    #pragma unroll
    for (int off = 32; off > 0; off >>= 1) sum += __shfl_xor(sum, off);
    p = p / sum;

    ps[wave][lane] = p;
    __syncthreads();

    // PV: lane = output dim d; V reads coalesced, ps broadcast from LDS.
    const int d = lane;
    float acc = 0.f;
    const int wstart = (t >= 63) ? 0 : (63 - t);
    const float* vcol = V + h * 64 + d;
    for (int w = wstart; w < 64; ++w) {
        const int ktw = t - 63 + w;
        acc = fmaf(ps[wave][w], vcol[(size_t)ktw * 512], acc);
    }
    O[(size_t)t * 512 + h * 64 + d] = acc;
}

extern "C" void kernel_launch(void* const* d_in, const int* in_sizes, int n_in,
                              void* d_out, int out_size, void* d_ws, size_t ws_size,
                              hipStream_t stream) {
    const float* x  = (const float*)d_in[0];
    const float* Wq = (const float*)d_in[1];
    const float* Wk = (const float*)d_in[2];
    const float* Wv = (const float*)d_in[3];
    const float* Wo = (const float*)d_in[4];
    float* out = (float*)d_out;

    const int D = 512;
    const int T = in_sizes[0] / D;   // 4096

    float* Qb = (float*)d_ws;
    float* Kb = Qb + (size_t)T * D;
    float* Vb = Kb + (size_t)T * D;
    float* Ab = Vb + (size_t)T * D;

    dim3 block(256);
    // QKV projections fused into one launch via grid.z
    gemm_nt_f32<<<dim3(D / TILE, T / TILE, 3), block, 0, stream>>>(
        x, Wq, Wk, Wv, Qb, Kb, Vb, T, D, D);
    // windowed attention: T*H waves, 4 waves/block, same-head t-blocking
    swattn_f32<<<dim3(8 * T / 4), block, 0, stream>>>(Qb, Kb, Vb, Ab, T);
    // output projection
    gemm_nt_f32<<<dim3(D / TILE, T / TILE, 1), block, 0, stream>>>(
        Ab, Wo, Wo, Wo, out, out, out, T, D, D);
}

// Round 3
// 204.631 us; speedup vs baseline: 1.7518x; 1.7518x over previous
//
#include <hip/hip_runtime.h>
#include <hip/hip_bf16.h>
#include <math.h>

// Round 3:
//  - GEMMs via split-bf16 MFMA (C = A@W^T = Ah@Wh^T + Ah@Wl^T + Al@Wh^T), fp32-quality.
//  - Attention: LDS-staged K/V window tiles (coalesced staging), 64 queries/block.

typedef __attribute__((ext_vector_type(8))) short bf16frag;  // 8 bf16 in 4 VGPRs
typedef __attribute__((ext_vector_type(4))) float f32x4;

__device__ inline unsigned short bf16_rne(float f) {
    unsigned int u = __float_as_uint(f);
    unsigned int r = u + 0x7fffu + ((u >> 16) & 1u);
    return (unsigned short)(r >> 16);
}

__device__ inline void split_val(float f, unsigned short& h, unsigned short& l) {
    h = bf16_rne(f);
    float hf = __uint_as_float(((unsigned int)h) << 16);
    float lf = f - hf;
    l = bf16_rne(lf);
}

// ---- fp32 -> (hi, lo) bf16 split: x + 4 weight matrices in one launch ----
__global__ __launch_bounds__(256) void split5(
    const float* __restrict__ x, const float* __restrict__ wq, const float* __restrict__ wk,
    const float* __restrict__ wv, const float* __restrict__ wo,
    unsigned short* xh, unsigned short* xl, unsigned short* qh, unsigned short* ql,
    unsigned short* kh, unsigned short* kl, unsigned short* vh, unsigned short* vl,
    unsigned short* oh, unsigned short* ol, int nx, int nw)
{
    const float* src; unsigned short *H, *L; int n;
    switch (blockIdx.z) {
        case 0: src = x;  H = xh; L = xl; n = nx; break;
        case 1: src = wq; H = qh; L = ql; n = nw; break;
        case 2: src = wk; H = kh; L = kl; n = nw; break;
        case 3: src = wv; H = vh; L = vl; n = nw; break;
        default: src = wo; H = oh; L = ol; n = nw; break;
    }
    int stride = gridDim.x * blockDim.x * 4;
    for (int i = (blockIdx.x * blockDim.x + threadIdx.x) * 4; i < n; i += stride) {
        float4 f = *(const float4*)(src + i);
        ushort4 h4, l4;
        split_val(f.x, h4.x, l4.x);
        split_val(f.y, h4.y, l4.y);
        split_val(f.z, h4.z, l4.z);
        split_val(f.w, h4.w, l4.w);
        *(ushort4*)(H + i) = h4;
        *(ushort4*)(L + i) = l4;
    }
}

__global__ __launch_bounds__(256) void split1(
    const float* __restrict__ src, unsigned short* H, unsigned short* L, int n)
{
    int stride = gridDim.x * blockDim.x * 4;
    for (int i = (blockIdx.x * blockDim.x + threadIdx.x) * 4; i < n; i += stride) {
        float4 f = *(const float4*)(src + i);
        ushort4 h4, l4;
        split_val(f.x, h4.x, l4.x);
        split_val(f.y, h4.y, l4.y);
        split_val(f.z, h4.z, l4.z);
        split_val(f.w, h4.w, l4.w);
        *(ushort4*)(H + i) = h4;
        *(ushort4*)(L + i) = l4;
    }
}

// ---- split-bf16 MFMA GEMM: C[M x 512] = A[M x 512] @ W[512 x 512]^T ----
// Block: 256 thr = 4 waves (2x2), block tile 128x128, wave tile 64x64 (4x4 frags of 16x16).
// K = 512 fixed. blockIdx.z selects (W, C) pair for fused QKV.
__global__ __launch_bounds__(256) void gemm_bf16s(
    const unsigned short* __restrict__ Ah, const unsigned short* __restrict__ Al,
    const unsigned short* __restrict__ W0h, const unsigned short* __restrict__ W0l,
    const unsigned short* __restrict__ W1h, const unsigned short* __restrict__ W1l,
    const unsigned short* __restrict__ W2h, const unsigned short* __restrict__ W2l,
    float* __restrict__ C0, float* __restrict__ C1, float* __restrict__ C2, int M)
{
    const unsigned short *Wh, *Wl; float* C;
    if (blockIdx.z == 0)      { Wh = W0h; Wl = W0l; C = C0; }
    else if (blockIdx.z == 1) { Wh = W1h; Wl = W1l; C = C1; }
    else                      { Wh = W2h; Wl = W2l; C = C2; }

    const int wid  = threadIdx.x >> 6;
    const int lane = threadIdx.x & 63;
    const int wr = wid >> 1, wc = wid & 1;
    const int m0 = blockIdx.y * 128 + wr * 64;
    const int n0 = blockIdx.x * 128 + wc * 64;
    const int lrow = lane & 15;
    const int lk   = (lane >> 4) << 3;   // k-offset 0,8,16,24

    const unsigned short* aH = Ah + (size_t)(m0 + lrow) * 512 + lk;
    const unsigned short* aL = Al + (size_t)(m0 + lrow) * 512 + lk;
    const unsigned short* bH = Wh + (size_t)(n0 + lrow) * 512 + lk;
    const unsigned short* bL = Wl + (size_t)(n0 + lrow) * 512 + lk;

    f32x4 acc[4][4];
    #pragma unroll
    for (int i = 0; i < 4; ++i)
        #pragma unroll
        for (int j = 0; j < 4; ++j)
            acc[i][j] = (f32x4){0.f, 0.f, 0.f, 0.f};

    #pragma unroll 2
    for (int k0 = 0; k0 < 512; k0 += 32) {
        bf16frag ah[4], al[4], bh[4], bl[4];
        #pragma unroll
        for (int mt = 0; mt < 4; ++mt) {
            ah[mt] = *(const bf16frag*)(aH + (size_t)mt * 16 * 512 + k0);
            al[mt] = *(const bf16frag*)(aL + (size_t)mt * 16 * 512 + k0);
            bh[mt] = *(const bf16frag*)(bH + (size_t)mt * 16 * 512 + k0);
            bl[mt] = *(const bf16frag*)(bL + (size_t)mt * 16 * 512 + k0);
        }
        #pragma unroll
        for (int mt = 0; mt < 4; ++mt)
            #pragma unroll
            for (int nt = 0; nt < 4; ++nt) {
                acc[mt][nt] = __builtin_amdgcn_mfma_f32_16x16x32_bf16(ah[mt], bh[nt], acc[mt][nt], 0, 0, 0);
                acc[mt][nt] = __builtin_amdgcn_mfma_f32_16x16x32_bf16(ah[mt], bl[nt], acc[mt][nt], 0, 0, 0);
                acc[mt][nt] = __builtin_amdgcn_mfma_f32_16x16x32_bf16(al[mt], bh[nt], acc[mt][nt], 0, 0, 0);
            }
    }

    // C/D layout (HW-verified): col = lane&15, row = (lane>>4)*4 + j
    const int rbase = (lane >> 4) * 4;
    #pragma unroll
    for (int mt = 0; mt < 4; ++mt)
        #pragma unroll
        for (int nt = 0; nt < 4; ++nt) {
            const int col = n0 + nt * 16 + lrow;
            #pragma unroll
            for (int j = 0; j < 4; ++j) {
                const int row = m0 + mt * 16 + rbase + j;
                C[(size_t)row * 512 + col] = acc[mt][nt][j];
            }
        }
}

// ---- windowed attention, LDS-staged K/V ----
// Block: head h, queries t0..t0+63. Stage K/V rows [t0-63, t0+63] (127 rows x 64 f32).
#define AP 68
__global__ __launch_bounds__(256) void swattn2(
    const float* __restrict__ Q, const float* __restrict__ K,
    const float* __restrict__ V, float* __restrict__ O, int T)
{
    __shared__ float Ks[127][AP];
    __shared__ float Vs[127][AP];
    __shared__ float ps[4][64];

    const int h  = blockIdx.x & 7;
    const int t0 = (blockIdx.x >> 3) * 64;
    const int kt0 = t0 - 63;
    const int tid = threadIdx.x;

    // coalesced staging: 16 threads per row, float4 each
    {
        const int r0 = tid >> 4;
        const int c  = (tid & 15) << 2;
        for (int r = r0; r < 127; r += 16) {
            const int kt = kt0 + r;
            float4 kv = {0.f, 0.f, 0.f, 0.f}, vv = {0.f, 0.f, 0.f, 0.f};
            if (kt >= 0) {
                kv = *(const float4*)(K + (size_t)kt * 512 + h * 64 + c);
                vv = *(const float4*)(V + (size_t)kt * 512 + h * 64 + c);
            }
            *(float4*)&Ks[r][c] = kv;
            *(float4*)&Vs[r][c] = vv;
        }
    }
    __syncthreads();

    const int wave = tid >> 6;
    const int lane = tid & 63;

    for (int s = 0; s < 16; ++s) {
        const int qi = wave * 16 + s;
        const int t  = t0 + qi;
        const float* qrow = Q + (size_t)t * 512 + h * 64;

        // QK^T: lane = window position
        const int kt = t - 63 + lane;
        const float* krow = &Ks[qi + lane][0];
        float acc = 0.f;
        #pragma unroll
        for (int d = 0; d < 64; d += 4) {
            float4 qa = *(const float4*)(qrow + d);
            float4 ka = *(const float4*)(krow + d);
            acc = fmaf(qa.x, ka.x, acc);
            acc = fmaf(qa.y, ka.y, acc);
            acc = fmaf(qa.z, ka.z, acc);
            acc = fmaf(qa.w, ka.w, acc);
        }
        float sc = (kt >= 0) ? acc * 0.125f : -INFINITY;

        // wave softmax
        float m = sc;
        #pragma unroll
        for (int off = 32; off > 0; off >>= 1) m = fmaxf(m, __shfl_xor(m, off));
        float p = (kt >= 0) ? __expf(sc - m) : 0.f;
        float sum = p;
        #pragma unroll
        for (int off = 32; off > 0; off >>= 1) sum += __shfl_xor(sum, off);
        p /= sum;
        ps[wave][lane] = p;   // intra-wave LDS dependency; compiler inserts lgkmcnt wait

        // PV: lane = head dim d; Vs reads bank-conflict-free (2 lanes/bank)
        float oacc = 0.f;
        #pragma unroll
        for (int w2 = 0; w2 < 64; w2 += 4) {
            float4 p4 = *(const float4*)&ps[wave][w2];
            oacc = fmaf(p4.x, Vs[qi + w2 + 0][lane], oacc);
            oacc = fmaf(p4.y, Vs[qi + w2 + 1][lane], oacc);
            oacc = fmaf(p4.z, Vs[qi + w2 + 2][lane], oacc);
            oacc = fmaf(p4.w, Vs[qi + w2 + 3][lane], oacc);
        }
        O[(size_t)t * 512 + h * 64 + lane] = oacc;
    }
}

extern "C" void kernel_launch(void* const* d_in, const int* in_sizes, int n_in,
                              void* d_out, int out_size, void* d_ws, size_t ws_size,
                              hipStream_t stream) {
    const float* x  = (const float*)d_in[0];
    const float* Wq = (const float*)d_in[1];
    const float* Wk = (const float*)d_in[2];
    const float* Wv = (const float*)d_in[3];
    const float* Wo = (const float*)d_in[4];
    float* out = (float*)d_out;

    const int D = 512;
    const int T = in_sizes[0] / D;     // 4096
    const size_t tdf = (size_t)T * D;  // 2,097,152
    const size_t wsz = (size_t)D * D;  //   262,144

    float* Qb = (float*)d_ws;
    float* Kb = Qb + tdf;
    float* Vb = Kb + tdf;
    float* Ab = Vb + tdf;
    unsigned short* xh  = (unsigned short*)(Ab + tdf);
    unsigned short* xl  = xh + tdf;
    unsigned short* abh = xl + tdf;
    unsigned short* abl = abh + tdf;
    unsigned short* wqh = abl + tdf;
    unsigned short* wql = wqh + wsz;
    unsigned short* wkh = wql + wsz;
    unsigned short* wkl = wkh + wsz;
    unsigned short* wvh = wkl + wsz;
    unsigned short* wvl = wvh + wsz;
    unsigned short* woh = wvl + wsz;
    unsigned short* wol = woh + wsz;
    // total ws use: 4*tdf*4 + 4*tdf*2 + 8*wsz*2 bytes ≈ 54.5 MB

    dim3 blk(256);
    split5<<<dim3(256, 1, 5), blk, 0, stream>>>(
        x, Wq, Wk, Wv, Wo, xh, xl, wqh, wql, wkh, wkl, wvh, wvl, woh, wol,
        (int)tdf, (int)wsz);

    gemm_bf16s<<<dim3(4, T / 128, 3), blk, 0, stream>>>(
        xh, xl, wqh, wql, wkh, wkl, wvh, wvl, Qb, Kb, Vb, T);

    swattn2<<<dim3(8 * T / 64), blk, 0, stream>>>(Qb, Kb, Vb, Ab, T);

    split1<<<dim3(512), blk, 0, stream>>>(Ab, abh, abl, (int)tdf);

    gemm_bf16s<<<dim3(4, T / 128, 1), blk, 0, stream>>>(
        abh, abl, woh, wol, woh, wol, woh, wol, out, out, out, T);
}